// Round 10
// baseline (432.123 us; speedup 1.0000x reference)
//
#include <hip/hip_runtime.h>

// nnmodel_35708358099045 R13: persistent grid-stride waves — break the convoy.
// Post-mortem R12: coalesced+LDS tied divergent R7 (147us) even with a scratch
// handicap -> line-divergence theory dead. The invariant across ALL ~147us
// kernels: 8 blocks/CU = ONE residency generation, all waves start t=0 with
// identical code/timing -> lock-step load-burst convoys -> HBM sees flood/lull
// cycles and sustains only ~2.0-2.6 TB/s. R6 (misses spread in time) sustained
// 3.4 TB/s on the same access family. Fix: 512 blocks (2/CU), each thread
// grid-strides 4 rows using the VERBATIM R7 body. After iter 1, per-wave
// latencies decohere the phases -> continuous steady demand at ideal traffic.
// No numerics change (FP order bit-identical to R5-R12), no LDS, no scratch
// arrays. One variable: phase structure.

#define HN 10
#define ND 40
#define HF 8
#define TPB 256
#define GRID 512

__global__ __launch_bounds__(TPB) void gnn_kernel(
    const float* __restrict__ x,          // [B, 40]
    const float* __restrict__ z,          // [B, 10, 8]
    const float* __restrict__ y,          // [B, 40]
    const float* __restrict__ enc_rel_w,  // [8, 1]
    const float* __restrict__ enc_rel_b,  // [8]
    const float* __restrict__ enc_root_w, // [8, 8]
    const float* __restrict__ pred_rel_w, // [8, 8]
    const float* __restrict__ pred_rel_b, // [8]
    const float* __restrict__ pred_root_w,// [8, 8]
    const float* __restrict__ dec_rel_w,  // [1, 8]
    const float* __restrict__ dec_rel_b,  // [1]
    const float* __restrict__ dec_root_w, // [1, 1]
    float* __restrict__ out,              // [B, 40]
    int B)
{
    const int tid = blockIdx.x * TPB + threadIdx.x;
    const long long RSTRIDE = (long long)GRID * TPB;   // 131072 rows

    const float w = 0.8948393168143698f;  // exp(-(1/3)^2) as fp32

    const float drb   = dec_rel_b[0];
    const float droot = dec_root_w[0];

    // encoder GraphConv row: r = relu(agg*erw + erb + z . enc_root_w)
    auto enc_row = [&](float aggv, float4 v0, float4 v1, float (&r)[HF]) {
        float zrow[HF] = {v0.x, v0.y, v0.z, v0.w, v1.x, v1.y, v1.z, v1.w};
        #pragma unroll
        for (int f = 0; f < HF; ++f) {
            float acc = aggv * enc_rel_w[f] + enc_rel_b[f];
            #pragma unroll
            for (int g = 0; g < HF; ++g)
                acc += zrow[g] * enc_root_w[f * HF + g];
            r[f] = fmaxf(acc, 0.0f);
        }
    };

    // predictor + decoder row-dot for center rc with neighbors rm, rp
    auto emit = [&](const float (&rm)[HF], const float (&rc)[HF],
                    const float (&rp)[HF]) -> float {
        float a2[HF];
        #pragma unroll
        for (int f = 0; f < HF; ++f)
            a2[f] = rc[f] + w * (rm[f] + rp[f]);
        float s = 0.0f;
        #pragma unroll
        for (int f = 0; f < HF; ++f) {
            float acc = pred_rel_b[f];
            #pragma unroll
            for (int g = 0; g < HF; ++g)
                acc += a2[g] * pred_rel_w[f * HF + g];
            #pragma unroll
            for (int g = 0; g < HF; ++g)
                acc += rc[g] * pred_root_w[f * HF + g];
            s += fmaxf(acc, 0.0f) * dec_rel_w[f];
        }
        return s;
    };

    // -------- persistent outer loop: 4 rows per thread, decohered ---------
    #pragma unroll 1
    for (long long e = tid; e < B; e += RSTRIDE) {
        const float4* xr = (const float4*)(x + e * ND);        // 10 float4
        const float4* zr = (const float4*)(z + e * (HN * HF)); // 20 float4
        const float4* yr = (const float4*)(y + e * ND);        // 10 float4
        float4*       og = (float4*)(out + e * ND);            // 10 float4

        auto store_out = [&](int idx, float sa, float sb, float4 yv) {
            const float pair = sa + sb + drb;
            float4 o;
            o.x = (sa + drb) + yv.x * droot;
            o.y = pair       + yv.y * droot;
            o.z = pair       + yv.z * droot;
            o.w = (sb + drb) + yv.w * droot;
            og[idx] = o;
        };

        // ---- x: own row, 10 x dwordx4, hot-line consumption ----
        float4 X0 = xr[0], X1 = xr[1], X2 = xr[2], X3 = xr[3], X4 = xr[4],
               X5 = xr[5], X6 = xr[6], X7 = xr[7], X8 = xr[8], X9 = xr[9];
        // agg[j] = X[j-1].y+.z+.w + X[j].x+.y+.z (cyclic), FP order as R5-R12
        const float a0 = X9.y + X9.z + X9.w + X0.x + X0.y + X0.z;
        const float a1 = X0.y + X0.z + X0.w + X1.x + X1.y + X1.z;
        const float a2v= X1.y + X1.z + X1.w + X2.x + X2.y + X2.z;
        const float a3 = X2.y + X2.z + X2.w + X3.x + X3.y + X3.z;
        const float a4 = X3.y + X3.z + X3.w + X4.x + X4.y + X4.z;
        const float a5 = X4.y + X4.z + X4.w + X5.x + X5.y + X5.z;
        const float a6 = X5.y + X5.z + X5.w + X6.x + X6.y + X6.z;
        const float a7 = X6.y + X6.z + X6.w + X7.x + X7.y + X7.z;
        const float a8 = X7.y + X7.z + X7.w + X8.x + X8.y + X8.z;
        const float a9 = X8.y + X8.z + X8.w + X9.x + X9.y + X9.z;

        float u0 = a2v, u1 = a3, u2 = a4, u3 = a5,
              u4 = a6,  u5 = a7, u6 = a8, u7 = a9;

        // ---- z nodes 0,1 (one 64B line) ----
        float r0s[HF], r1s[HF];
        {
            float4 zq0 = zr[0], zq1 = zr[1], zq2 = zr[2], zq3 = zr[3];
            enc_row(a0, zq0, zq1, r0s);
            enc_row(a1, zq2, zq3, r1s);
        }

        float rm[HF], rc[HF];
        #pragma unroll
        for (int f = 0; f < HF; ++f) { rm[f] = r0s[f]; rc[f] = r1s[f]; }

        // s2[1..8] shift queue
        float t0 = 0.f, t1 = 0.f, t2 = 0.f, t3 = 0.f,
              t4 = 0.f, t5 = 0.f, t6 = 0.f, t7 = 0.f;

        // ---- inner loop: j=1..4, nodes (2j, 2j+1), one z line per iter ----
        #pragma unroll 1
        for (int j = 1; j <= 4; ++j) {
            float4 q0 = zr[4*j + 0], q1 = zr[4*j + 1],
                   q2 = zr[4*j + 2], q3 = zr[4*j + 3];   // one 64B line

            float rp0[HF], rp1[HF];
            enc_row(u0, q0, q1, rp0);                    // node 2j
            enc_row(u1, q2, q3, rp1);                    // node 2j+1

            const float sA = emit(rm, rc, rp0);          // s2[2j-1]
            const float sB = emit(rc, rp0, rp1);         // s2[2j]

            // shift queues (compile-time names -> pure v_mov, no scratch)
            t0 = t2; t1 = t3; t2 = t4; t3 = t5; t4 = t6; t5 = t7;
            t6 = sA; t7 = sB;
            u0 = u2; u1 = u3; u2 = u4; u3 = u5; u4 = u6; u5 = u7;
            #pragma unroll
            for (int f = 0; f < HF; ++f) { rm[f] = rp0[f]; rc[f] = rp1[f]; }
        }
        // after loop: rm=r[8], rc=r[9]; t0..t7 = s2[1..8]

        // ---- epilogue: y early (overlaps tail emits), wrap emits ----
        float4 Y0 = yr[0], Y1 = yr[1], Y2 = yr[2], Y3 = yr[3], Y4 = yr[4],
               Y5 = yr[5], Y6 = yr[6], Y7 = yr[7], Y8 = yr[8], Y9 = yr[9];

        const float s9 = emit(rm, rc, r0s);              // s2[9]
        const float s0 = emit(rc, r0s, r1s);             // s2[0]

        // straight-line full-row store: 10 full float4, back-to-back
        store_out(0, s0, t0, Y0);
        store_out(1, t0, t1, Y1);
        store_out(2, t1, t2, Y2);
        store_out(3, t2, t3, Y3);
        store_out(4, t3, t4, Y4);
        store_out(5, t4, t5, Y5);
        store_out(6, t5, t6, Y6);
        store_out(7, t6, t7, Y7);
        store_out(8, t7, s9, Y8);
        store_out(9, s9, s0, Y9);
    }
}

extern "C" void kernel_launch(void* const* d_in, const int* in_sizes, int n_in,
                              void* d_out, int out_size, void* d_ws, size_t ws_size,
                              hipStream_t stream) {
    const float* x          = (const float*)d_in[0];
    const float* z          = (const float*)d_in[1];
    const float* y          = (const float*)d_in[2];
    const float* enc_rel_w  = (const float*)d_in[3];
    const float* enc_rel_b  = (const float*)d_in[4];
    const float* enc_root_w = (const float*)d_in[5];
    const float* pred_rel_w = (const float*)d_in[6];
    const float* pred_rel_b = (const float*)d_in[7];
    const float* pred_root_w= (const float*)d_in[8];
    const float* dec_rel_w  = (const float*)d_in[9];
    const float* dec_rel_b  = (const float*)d_in[10];
    const float* dec_root_w = (const float*)d_in[11];
    float* out = (float*)d_out;

    const int B = in_sizes[0] / ND;       // 524288
    gnn_kernel<<<GRID, TPB, 0, stream>>>(
        x, z, y, enc_rel_w, enc_rel_b, enc_root_w,
        pred_rel_w, pred_rel_b, pred_root_w,
        dec_rel_w, dec_rel_b, dec_root_w, out, B);
}

// Round 11
// 373.157 us; speedup vs baseline: 1.1580x; 1.1580x over previous
//
#include <hip/hip_runtime.h>

// nnmodel_35708358099045 R14: clean coalesced (R12 minus the spill).
// Transaction-rate model (fits all 11 runs): per-CU memory pipe serves
// ~0.16-0.25 transactions/cy regardless of size. R7 issues 40 divergent
// dwordx4/thread = 2560 x 16B requests/wave = 0.23 req/cy/CU -> transaction
// -bound at 27% HBM. Coalesced instrs merge to ~16 x 64B -> 4x fewer.
// R12 tested this but spilled ~44 regs (VGPR 92, WRITE 176MB, +80 mem
// instr/thread) cancelling the gain. R14 removes the register hogs:
//  - x readback: rolling 2-float4 window (no xv[40]); aggs on the fly.
//  - out staging: named scalars, no sa[10]/sb[10] arrays.
//  - y: 10 named float4 regs loaded under the tail emits.
// Validity gate: WRITE ~84-87 MB, VGPR <=110. Prediction if theory holds:
// 95-120 us. FP order bit-identical to R5-R13.

#define HN 10
#define ND 40
#define HF 8
#define TPB 256
#define WLEN 64
#define ROW4 11   // padded row stride in float4 (x / out staging)
#define ZROW 5    // padded z-slice stride in float4

__global__ __launch_bounds__(TPB) void gnn_kernel(
    const float* __restrict__ x,          // [B, 40]
    const float* __restrict__ z,          // [B, 10, 8]
    const float* __restrict__ y,          // [B, 40]
    const float* __restrict__ enc_rel_w,  // [8, 1]
    const float* __restrict__ enc_rel_b,  // [8]
    const float* __restrict__ enc_root_w, // [8, 8]
    const float* __restrict__ pred_rel_w, // [8, 8]
    const float* __restrict__ pred_rel_b, // [8]
    const float* __restrict__ pred_root_w,// [8, 8]
    const float* __restrict__ dec_rel_w,  // [1, 8]
    const float* __restrict__ dec_rel_b,  // [1]
    const float* __restrict__ dec_root_w, // [1, 1]
    float* __restrict__ out,              // [B, 40]
    int B)
{
    __shared__ float4 lds4[TPB * ROW4];   // 45056 B: 704 float4 per wave
    const int t  = threadIdx.x;
    const int l  = t & 63;
    const int wv = t >> 6;
    const long long W = (long long)blockIdx.x * TPB + wv * WLEN; // wave row base
    float4* wl = lds4 + wv * (WLEN * ROW4);

    const float w = 0.8948393168143698f;  // exp(-(1/3)^2) as fp32

    const float4* xg4 = (const float4*)x;   // row r = 10 float4 at r*10
    const float4* zg4 = (const float4*)z;   // row r = 20 float4 at r*20
    const float4* yg4 = (const float4*)y;
    float4*       og4 = (float4*)out;

    const float drb   = dec_rel_b[0];
    const float droot = dec_root_w[0];

    auto enc_row = [&](float aggv, float4 v0, float4 v1, float (&r)[HF]) {
        float zrow[HF] = {v0.x, v0.y, v0.z, v0.w, v1.x, v1.y, v1.z, v1.w};
        #pragma unroll
        for (int f = 0; f < HF; ++f) {
            float acc = aggv * enc_rel_w[f] + enc_rel_b[f];
            #pragma unroll
            for (int g = 0; g < HF; ++g)
                acc += zrow[g] * enc_root_w[f * HF + g];
            r[f] = fmaxf(acc, 0.0f);
        }
    };

    auto emit = [&](const float (&rm)[HF], const float (&rc)[HF],
                    const float (&rp)[HF]) -> float {
        float a2[HF];
        #pragma unroll
        for (int f = 0; f < HF; ++f)
            a2[f] = rc[f] + w * (rm[f] + rp[f]);
        float s = 0.0f;
        #pragma unroll
        for (int f = 0; f < HF; ++f) {
            float acc = pred_rel_b[f];
            #pragma unroll
            for (int g = 0; g < HF; ++g)
                acc += a2[g] * pred_rel_w[f * HF + g];
            #pragma unroll
            for (int g = 0; g < HF; ++g)
                acc += rc[g] * pred_root_w[f * HF + g];
            s += fmaxf(acc, 0.0f) * dec_rel_w[f];
        }
        return s;
    };

    // ---- X phase: coalesced load (16-line instrs) staged to padded LDS ----
    const long long xw = W * 10 + l;          // this lane's first float4
    #pragma unroll
    for (int k = 0; k < 10; ++k) {
        int i = l + 64 * k; int r = i / 10, q = i - r * 10;
        wl[r * ROW4 + q] = xg4[W * 10 + i];
    }
    // issue z line-0 loads now (coalesced; 4 lanes/line merge) so they fly
    // during the x transpose-readback + aggs
    const int  zbr = l >> 2, zm = l & 3;      // base row-in-wave, slot
    const long long zb = (W + zbr) * 20 + zm; // lane's z float4 base
    float4 zt0 = zg4[zb +   0];               // line 0, rows zbr+0
    float4 zt1 = zg4[zb + 320];               //          rows zbr+16
    float4 zt2 = zg4[zb + 640];               //          rows zbr+32
    float4 zt3 = zg4[zb + 960];               //          rows zbr+48
    asm volatile("s_waitcnt lgkmcnt(0)" ::: "memory");
    __builtin_amdgcn_sched_barrier(0);

    // rolling-window readback: 2 live float4, aggs on the fly (no xv[40])
    float a_[10];
    {
        float4 prev = wl[l * ROW4 + 9];       // X9
        #pragma unroll
        for (int k = 0; k < 10; ++k) {
            float4 cur = wl[l * ROW4 + k];
            // FP order identical to R5-R13: X[k-1].y+z+w + X[k].x+y+z
            a_[k] = prev.y + prev.z + prev.w + cur.x + cur.y + cur.z;
            prev = cur;
        }
    }
    float u0 = a_[2], u1 = a_[3], u2 = a_[4], u3 = a_[5],
          u4 = a_[6], u5 = a_[7], u6 = a_[8], u7 = a_[9];

    // ---- z iter 0 (peeled): write line0 -> buf0, issue line1, consume ----
    // x-LDS dead. buf0 = wl[0..319], buf1 = wl[320..639] (float4 units).
    wl[(zbr +  0) * ZROW + zm] = zt0;
    wl[(zbr + 16) * ZROW + zm] = zt1;
    wl[(zbr + 32) * ZROW + zm] = zt2;
    wl[(zbr + 48) * ZROW + zm] = zt3;
    zt0 = zg4[zb +   0 + 4];                  // line 1 in flight
    zt1 = zg4[zb + 320 + 4];
    zt2 = zg4[zb + 640 + 4];
    zt3 = zg4[zb + 960 + 4];
    asm volatile("s_waitcnt lgkmcnt(0)" ::: "memory");
    __builtin_amdgcn_sched_barrier(0);
    float r0s[HF], r1s[HF];
    {
        float4 q0 = wl[l * ZROW + 0], q1 = wl[l * ZROW + 1],
               q2 = wl[l * ZROW + 2], q3 = wl[l * ZROW + 3];
        enc_row(a_[0], q0, q1, r0s);
        enc_row(a_[1], q2, q3, r1s);
    }
    float rm[HF], rc[HF];
    #pragma unroll
    for (int f = 0; f < HF; ++f) { rm[f] = r0s[f]; rc[f] = r1s[f]; }

    float t0 = 0.f, t1 = 0.f, t2 = 0.f, t3 = 0.f,
          t4 = 0.f, t5 = 0.f, t6 = 0.f, t7 = 0.f;

    // ---- loop j=1..4: write line j (dbuf), issue line j+1, consume ----
    #pragma unroll 1
    for (int j = 1; j <= 4; ++j) {
        float4* bw = wl + (j & 1) * (WLEN * ZROW);
        bw[(zbr +  0) * ZROW + zm] = zt0;     // vmcnt-waits line j
        bw[(zbr + 16) * ZROW + zm] = zt1;
        bw[(zbr + 32) * ZROW + zm] = zt2;
        bw[(zbr + 48) * ZROW + zm] = zt3;
        if (j < 4) {
            zt0 = zg4[zb +   0 + 4 * (j + 1)];
            zt1 = zg4[zb + 320 + 4 * (j + 1)];
            zt2 = zg4[zb + 640 + 4 * (j + 1)];
            zt3 = zg4[zb + 960 + 4 * (j + 1)];
        }
        asm volatile("s_waitcnt lgkmcnt(0)" ::: "memory");
        __builtin_amdgcn_sched_barrier(0);
        float4 q0 = bw[l * ZROW + 0], q1 = bw[l * ZROW + 1],
               q2 = bw[l * ZROW + 2], q3 = bw[l * ZROW + 3];

        float rp0[HF], rp1[HF];
        enc_row(u0, q0, q1, rp0);             // node 2j
        enc_row(u1, q2, q3, rp1);             // node 2j+1
        const float sA = emit(rm, rc, rp0);   // s2[2j-1]
        const float sB = emit(rc, rp0, rp1);  // s2[2j]

        t0 = t2; t1 = t3; t2 = t4; t3 = t5; t4 = t6; t5 = t7;
        t6 = sA; t7 = sB;
        u0 = u2; u1 = u3; u2 = u4; u3 = u5; u4 = u6; u5 = u7;
        #pragma unroll
        for (int f = 0; f < HF; ++f) { rm[f] = rp0[f]; rc[f] = rp1[f]; }
    }
    // rm=r[8], rc=r[9]; t0..t7 = s2[1..8]

    // ---- epilogue: y coalesced into named regs (fly under tail emits) ----
    float4 Y0 = yg4[xw +   0], Y1 = yg4[xw +  64], Y2 = yg4[xw + 128],
           Y3 = yg4[xw + 192], Y4 = yg4[xw + 256], Y5 = yg4[xw + 320],
           Y6 = yg4[xw + 384], Y7 = yg4[xw + 448], Y8 = yg4[xw + 512],
           Y9 = yg4[xw + 576];

    const float s9 = emit(rm, rc, r0s);       // s2[9]
    const float s0 = emit(rc, r0s, r1s);      // s2[0]

    // stage out partials in 11-pad layout, named scalars only
    auto stage_pair = [&](int k, float sa, float sb) {
        const float pair = sa + sb + drb;
        float4 vo;
        vo.x = sa + drb;
        vo.y = pair;
        vo.z = pair;
        vo.w = sb + drb;
        wl[l * ROW4 + k] = vo;                // conflict-free b128
    };
    stage_pair(0, s0, t0);
    stage_pair(1, t0, t1);
    stage_pair(2, t1, t2);
    stage_pair(3, t2, t3);
    stage_pair(4, t3, t4);
    stage_pair(5, t4, t5);
    stage_pair(6, t5, t6);
    stage_pair(7, t6, t7);
    stage_pair(8, t7, s9);
    stage_pair(9, s9, s0);
    asm volatile("s_waitcnt lgkmcnt(0)" ::: "memory");
    __builtin_amdgcn_sched_barrier(0);

    // drain: coalesced full-line stores (merged 64B transactions)
    auto drain = [&](int k, float4 vy) {
        int i = l + 64 * k; int r = i / 10, q = i - r * 10;
        float4 p = wl[r * ROW4 + q];          // near-sequential, conflict-free
        p.x += vy.x * droot;
        p.y += vy.y * droot;
        p.z += vy.z * droot;
        p.w += vy.w * droot;
        og4[W * 10 + i] = p;
    };
    drain(0, Y0); drain(1, Y1); drain(2, Y2); drain(3, Y3); drain(4, Y4);
    drain(5, Y5); drain(6, Y6); drain(7, Y7); drain(8, Y8); drain(9, Y9);
}

extern "C" void kernel_launch(void* const* d_in, const int* in_sizes, int n_in,
                              void* d_out, int out_size, void* d_ws, size_t ws_size,
                              hipStream_t stream) {
    const float* x          = (const float*)d_in[0];
    const float* z          = (const float*)d_in[1];
    const float* y          = (const float*)d_in[2];
    const float* enc_rel_w  = (const float*)d_in[3];
    const float* enc_rel_b  = (const float*)d_in[4];
    const float* enc_root_w = (const float*)d_in[5];
    const float* pred_rel_w = (const float*)d_in[6];
    const float* pred_rel_b = (const float*)d_in[7];
    const float* pred_root_w= (const float*)d_in[8];
    const float* dec_rel_w  = (const float*)d_in[9];
    const float* dec_rel_b  = (const float*)d_in[10];
    const float* dec_root_w = (const float*)d_in[11];
    float* out = (float*)d_out;

    const int B = in_sizes[0] / ND;       // 524288, divisible by TPB
    const int blocks = B / TPB;           // 2048
    gnn_kernel<<<blocks, TPB, 0, stream>>>(
        x, z, y, enc_rel_w, enc_rel_b, enc_root_w,
        pred_rel_w, pred_rel_b, pred_root_w,
        dec_rel_w, dec_rel_b, dec_root_w, out, B);
}